// Round 1
// baseline (327.007 us; speedup 1.0000x reference)
//
#include <hip/hip_runtime.h>
#include <math.h>

// Problem constants
#define B_ 2
#define M_ 4
#define C_ 64
#define V_ 110592   // 48*48*48
#define K_ 4
#define EPS_ 1e-6f

// Workspace layout (floats):
//   num  : [B*M*K*C] = 2048  at offset 0
//   tw   : [B*M*K]   = 32    at offset 2048
//   cnt  : [B*K]     = 8     at offset 2080
#define WS_NUM 0
#define WS_TW  2048
#define WS_CNT 2080
#define WS_TOTAL 2088

__constant__ int PM_[6] = {0,0,0,1,1,2};
__constant__ int PN_[6] = {1,2,3,2,3,3};

// ---------------------------------------------------------------------------
// Kernel A: tw[b,m,k] = sum_v w * onehot ; count[b,k] = sum_v onehot
// grid = B*M * SA blocks, 256 threads
// ---------------------------------------------------------------------------
__global__ __launch_bounds__(256) void stats_kernel(
    const float* __restrict__ w, const int* __restrict__ tgt,
    float* __restrict__ ws)
{
    const int SA = 27;
    int bm = blockIdx.x / SA;
    int s  = blockIdx.x % SA;
    int b  = bm >> 2;

    const int vec_per = V_ / 4;        // 27648
    const int chunk   = vec_per / SA;  // 1024

    const float4* w4 = (const float4*)(w + (size_t)bm * V_);
    const int4*   t4 = (const int4*)(tgt + (size_t)b * V_);

    float tw0=0.f, tw1=0.f, tw2=0.f, tw3=0.f;
    int   c0=0, c1=0, c2=0, c3=0;

    int end = (s + 1) * chunk;
    for (int i = s * chunk + threadIdx.x; i < end; i += 256) {
        float4 wv = w4[i];
        int4   kv = t4[i];
        tw0 += (kv.x==0?wv.x:0.f) + (kv.y==0?wv.y:0.f) + (kv.z==0?wv.z:0.f) + (kv.w==0?wv.w:0.f);
        tw1 += (kv.x==1?wv.x:0.f) + (kv.y==1?wv.y:0.f) + (kv.z==1?wv.z:0.f) + (kv.w==1?wv.w:0.f);
        tw2 += (kv.x==2?wv.x:0.f) + (kv.y==2?wv.y:0.f) + (kv.z==2?wv.z:0.f) + (kv.w==2?wv.w:0.f);
        tw3 += (kv.x==3?wv.x:0.f) + (kv.y==3?wv.y:0.f) + (kv.z==3?wv.z:0.f) + (kv.w==3?wv.w:0.f);
        c0 += (kv.x==0) + (kv.y==0) + (kv.z==0) + (kv.w==0);
        c1 += (kv.x==1) + (kv.y==1) + (kv.z==1) + (kv.w==1);
        c2 += (kv.x==2) + (kv.y==2) + (kv.z==2) + (kv.w==2);
        c3 += (kv.x==3) + (kv.y==3) + (kv.z==3) + (kv.w==3);
    }

    // wave(64) shuffle reduce
    for (int off = 32; off; off >>= 1) {
        tw0 += __shfl_down(tw0, off); tw1 += __shfl_down(tw1, off);
        tw2 += __shfl_down(tw2, off); tw3 += __shfl_down(tw3, off);
        c0  += __shfl_down(c0,  off); c1  += __shfl_down(c1,  off);
        c2  += __shfl_down(c2,  off); c3  += __shfl_down(c3,  off);
    }
    __shared__ float s_tw[4][4];
    __shared__ int   s_c[4][4];
    int wid = threadIdx.x >> 6, lane = threadIdx.x & 63;
    if (lane == 0) {
        s_tw[wid][0]=tw0; s_tw[wid][1]=tw1; s_tw[wid][2]=tw2; s_tw[wid][3]=tw3;
        s_c[wid][0]=c0;   s_c[wid][1]=c1;   s_c[wid][2]=c2;   s_c[wid][3]=c3;
    }
    __syncthreads();
    if (threadIdx.x < 4) {
        int k = threadIdx.x;
        float t = s_tw[0][k] + s_tw[1][k] + s_tw[2][k] + s_tw[3][k];
        atomicAdd(&ws[WS_TW + bm*4 + k], t);
        if ((bm & 3) == 0) {  // m == 0: count is m-independent
            int cc = s_c[0][k] + s_c[1][k] + s_c[2][k] + s_c[3][k];
            atomicAdd(&ws[WS_CNT + b*4 + k], (float)cc);
        }
    }
}

// ---------------------------------------------------------------------------
// Kernel B: num[b,m,k,c] = sum_v f[b,m,c,v]*w[b,m,v]*onehot[k]
// grid = B*M * C * S ; block handles one (bm, c, chunk-of-V)
// ---------------------------------------------------------------------------
__global__ __launch_bounds__(256) void num_kernel(
    const float* __restrict__ f, const float* __restrict__ w,
    const int* __restrict__ tgt, float* __restrict__ ws)
{
    const int S = 4;
    int idx = blockIdx.x;
    int s  = idx & 3;
    int c  = (idx >> 2) & 63;
    int bm = idx >> 8;
    int b  = bm >> 2;

    const int vec_per = V_ / 4;       // 27648
    const int chunk   = vec_per / S;  // 6912

    const float4* f4 = (const float4*)(f + ((size_t)bm * C_ + c) * V_);
    const float4* w4 = (const float4*)(w + (size_t)bm * V_);
    const int4*   t4 = (const int4*)(tgt + (size_t)b * V_);

    float a0=0.f, a1=0.f, a2=0.f, a3=0.f;
    int end = (s + 1) * chunk;
    for (int i = s * chunk + threadIdx.x; i < end; i += 256) {
        float4 fv = f4[i];
        float4 wv = w4[i];
        int4   kv = t4[i];
        float p0 = fv.x * wv.x;
        float p1 = fv.y * wv.y;
        float p2 = fv.z * wv.z;
        float p3 = fv.w * wv.w;
        a0 += (kv.x==0?p0:0.f) + (kv.y==0?p1:0.f) + (kv.z==0?p2:0.f) + (kv.w==0?p3:0.f);
        a1 += (kv.x==1?p0:0.f) + (kv.y==1?p1:0.f) + (kv.z==1?p2:0.f) + (kv.w==1?p3:0.f);
        a2 += (kv.x==2?p0:0.f) + (kv.y==2?p1:0.f) + (kv.z==2?p2:0.f) + (kv.w==2?p3:0.f);
        a3 += (kv.x==3?p0:0.f) + (kv.y==3?p1:0.f) + (kv.z==3?p2:0.f) + (kv.w==3?p3:0.f);
    }

    for (int off = 32; off; off >>= 1) {
        a0 += __shfl_down(a0, off); a1 += __shfl_down(a1, off);
        a2 += __shfl_down(a2, off); a3 += __shfl_down(a3, off);
    }
    __shared__ float s_red[4][4];
    int wid = threadIdx.x >> 6, lane = threadIdx.x & 63;
    if (lane == 0) {
        s_red[wid][0]=a0; s_red[wid][1]=a1; s_red[wid][2]=a2; s_red[wid][3]=a3;
    }
    __syncthreads();
    if (threadIdx.x < 4) {
        int k = threadIdx.x;
        float v = s_red[0][k] + s_red[1][k] + s_red[2][k] + s_red[3][k];
        atomicAdd(&ws[WS_NUM + (bm*4 + k)*C_ + c], v);
    }
}

// ---------------------------------------------------------------------------
// Kernel C: finalize — prototypes, normalize, align/sep sums, scalar out
// one block, 256 threads
// ---------------------------------------------------------------------------
__global__ __launch_bounds__(256) void finalize_kernel(
    const float* __restrict__ ws, float* __restrict__ out)
{
    const float* num = ws + WS_NUM;
    const float* tw  = ws + WS_TW;
    const float* cnt = ws + WS_CNT;

    __shared__ float sp[2048];      // proto [32][64]
    __shared__ float s_scale[32];
    __shared__ float s_om[32];
    __shared__ int   s_valid[32];

    int tid = threadIdx.x;

    // raw proto = num / (tw + EPS)
    for (int i = tid; i < 2048; i += 256) {
        int p = i >> 6;
        sp[i] = num[i] / (tw[p] + EPS_);
    }
    __syncthreads();

    // per-prototype normalization scale, omega, valid
    if (tid < 32) {
        float ss = 0.f;
        for (int c = 0; c < 64; ++c) { float v = sp[tid*64 + c]; ss += v*v; }
        float norm = sqrtf(fmaxf(ss, 1e-24f));          // NORM_EPS^2
        s_scale[tid] = 1.0f / fmaxf(norm, 1e-12f);
        int b = tid >> 4;       // p = (b*4+m)*4+k
        int k = tid & 3;
        float cc = cnt[b*4 + k];
        s_om[tid] = (tw[tid] + EPS_) / (cc + EPS_);
        s_valid[tid] = (cc >= 1.0f) && (k != 0);
    }
    __syncthreads();
    for (int i = tid; i < 2048; i += 256) sp[i] *= s_scale[i >> 6];
    __syncthreads();

    float aS = 0.f, aC = 0.f, sS = 0.f, sC = 0.f;

    // align: 48 tuples = b(2) x mn-pair(6) x k(4)
    if (tid < 48) {
        int b = tid / 24, r = tid % 24;
        int pr = r >> 2, k = r & 3;
        int p1 = (b*4 + PM_[pr])*4 + k;
        int p2 = (b*4 + PN_[pr])*4 + k;
        if (s_valid[p1] && s_valid[p2]) {
            float d = 0.f;
            for (int c = 0; c < 64; ++c) d += sp[p1*64 + c] * sp[p2*64 + c];
            aS = s_om[p1] * s_om[p2] * fmaxf(0.9f - d, 0.f);
            aC = 1.f;
        }
    } else if (tid >= 64 && tid < 112) {
        // sep: 48 tuples = b(2) x m(4) x kl-pair(6)
        int t = tid - 64;
        int b = t / 24, r = t % 24;
        int m = r / 6, pr = r % 6;
        int bm = b*4 + m;
        int p1 = bm*4 + PM_[pr];
        int p2 = bm*4 + PN_[pr];
        if (s_valid[p1] && s_valid[p2]) {
            float d = 0.f;
            for (int c = 0; c < 64; ++c) d += sp[p1*64 + c] * sp[p2*64 + c];
            sS = fmaxf(d - 0.1f, 0.f);
            sC = 1.f;
        }
    }

    for (int off = 32; off; off >>= 1) {
        aS += __shfl_down(aS, off); aC += __shfl_down(aC, off);
        sS += __shfl_down(sS, off); sC += __shfl_down(sC, off);
    }
    __shared__ float red[4][4];
    int wid = tid >> 6, lane = tid & 63;
    if (lane == 0) { red[wid][0]=aS; red[wid][1]=aC; red[wid][2]=sS; red[wid][3]=sC; }
    __syncthreads();
    if (tid == 0) {
        float AS=0.f, AC=0.f, SS=0.f, SC=0.f;
        for (int i = 0; i < 4; ++i) { AS+=red[i][0]; AC+=red[i][1]; SS+=red[i][2]; SC+=red[i][3]; }
        out[0] = AS / (AC + EPS_) + SS / (SC + EPS_);
    }
}

extern "C" void kernel_launch(void* const* d_in, const int* in_sizes, int n_in,
                              void* d_out, int out_size, void* d_ws, size_t ws_size,
                              hipStream_t stream)
{
    const float* feats   = (const float*)d_in[0];
    const float* weights = (const float*)d_in[1];
    const int*   target  = (const int*)d_in[2];
    float* out = (float*)d_out;
    float* ws  = (float*)d_ws;

    hipMemsetAsync(d_ws, 0, WS_TOTAL * sizeof(float), stream);
    stats_kernel<<<B_*M_*27, 256, 0, stream>>>(weights, target, ws);
    num_kernel<<<B_*M_*C_*4, 256, 0, stream>>>(feats, weights, target, ws);
    finalize_kernel<<<1, 256, 0, stream>>>(ws, out);
}

// Round 2
// 307.366 us; speedup vs baseline: 1.0639x; 1.0639x over previous
//
#include <hip/hip_runtime.h>
#include <math.h>

// Problem constants
#define B_ 2
#define M_ 4
#define C_ 64
#define V_ 110592   // 48*48*48
#define EPS_ 1e-6f

// Workspace layout (floats) — all slots written every call (no memset needed):
//   P_NUM : per-block num partials [bm(8)][c(64)][s(4)][k(4)] = 8192
//   P_TW  : tw partials            [bm(8)][s(4)][k(4)]        = 128
//   P_CNT : count partials         [b(2)][s(4)][k(4)]         = 32
#define P_NUM 0
#define P_TW  8192
#define P_CNT 8320

__constant__ int PM_[6] = {0,0,0,1,1,2};
__constant__ int PN_[6] = {1,2,3,2,3,3};

typedef float  fvec4 __attribute__((ext_vector_type(4)));

// ---------------------------------------------------------------------------
// Main kernel: fused stats + num partials.
// grid = bm(8) x ch(32) x s(4) = 1024 blocks, 256 threads.
// Each block: channels {ch, ch+32} of modality bm, V-chunk s (1/4 of V).
// c==0 blocks additionally compute tw / count partials (they read w,t anyway).
// ---------------------------------------------------------------------------
__global__ __launch_bounds__(256) void main_kernel(
    const float* __restrict__ f, const float* __restrict__ w,
    const int* __restrict__ tgt, float* __restrict__ ws)
{
    int idx = blockIdx.x;
    int s  = idx & 3;
    int ch = (idx >> 2) & 31;
    int bm = idx >> 7;
    int b  = bm >> 2;
    const bool do_stats = (ch == 0);

    const int chunk = (V_ / 4) / 4;   // 6912 float4 per s-chunk

    const fvec4* fa = (const fvec4*)(f + ((size_t)bm * C_ + ch) * V_);
    const fvec4* fb = (const fvec4*)(f + ((size_t)bm * C_ + ch + 32) * V_);
    const float4* w4 = (const float4*)(w + (size_t)bm * V_);
    const int4*   t4 = (const int4*)(tgt + (size_t)b * V_);

    float A[8] = {0,0,0,0,0,0,0,0};
    float tw[4] = {0,0,0,0};
    int   cn[4] = {0,0,0,0};

    int beg = s * chunk, end = beg + chunk;
    for (int i = beg + (int)threadIdx.x; i < end; i += 256) {
        fvec4  va = __builtin_nontemporal_load(&fa[i]);   // streaming: keep w/t in L2
        fvec4  vb = __builtin_nontemporal_load(&fb[i]);
        float4 wv = w4[i];
        int4   kv = t4[i];
        float pa0 = va.x * wv.x, pa1 = va.y * wv.y, pa2 = va.z * wv.z, pa3 = va.w * wv.w;
        float pb0 = vb.x * wv.x, pb1 = vb.y * wv.y, pb2 = vb.z * wv.z, pb3 = vb.w * wv.w;
        #pragma unroll
        for (int k = 0; k < 4; ++k) {
            A[k]     += (kv.x==k?pa0:0.f) + (kv.y==k?pa1:0.f) + (kv.z==k?pa2:0.f) + (kv.w==k?pa3:0.f);
            A[4 + k] += (kv.x==k?pb0:0.f) + (kv.y==k?pb1:0.f) + (kv.z==k?pb2:0.f) + (kv.w==k?pb3:0.f);
        }
        if (do_stats) {
            #pragma unroll
            for (int k = 0; k < 4; ++k) {
                tw[k] += (kv.x==k?wv.x:0.f) + (kv.y==k?wv.y:0.f) + (kv.z==k?wv.z:0.f) + (kv.w==k?wv.w:0.f);
                cn[k] += (kv.x==k) + (kv.y==k) + (kv.z==k) + (kv.w==k);
            }
        }
    }

    // wave(64) shuffle reduce
    #pragma unroll
    for (int off = 32; off; off >>= 1) {
        #pragma unroll
        for (int j = 0; j < 8; ++j) A[j] += __shfl_down(A[j], off);
        if (do_stats) {
            #pragma unroll
            for (int k = 0; k < 4; ++k) {
                tw[k] += __shfl_down(tw[k], off);
                cn[k] += __shfl_down(cn[k], off);
            }
        }
    }

    __shared__ float sA[4][8];
    __shared__ float sT[4][4];
    __shared__ int   sC[4][4];
    int wid = threadIdx.x >> 6, lane = threadIdx.x & 63;
    if (lane == 0) {
        #pragma unroll
        for (int j = 0; j < 8; ++j) sA[wid][j] = A[j];
        if (do_stats) {
            #pragma unroll
            for (int k = 0; k < 4; ++k) { sT[wid][k] = tw[k]; sC[wid][k] = cn[k]; }
        }
    }
    __syncthreads();

    if (threadIdx.x < 8) {
        int j = threadIdx.x;
        int k = j & 3;
        int c = ch + (j >> 2) * 32;
        float v = sA[0][j] + sA[1][j] + sA[2][j] + sA[3][j];
        ws[P_NUM + ((bm * C_ + c) * 4 + s) * 4 + k] = v;
    }
    if (do_stats && threadIdx.x < 4) {
        int k = threadIdx.x;
        float t = sT[0][k] + sT[1][k] + sT[2][k] + sT[3][k];
        ws[P_TW + (bm * 4 + s) * 4 + k] = t;
        if ((bm & 3) == 0) {
            int cc = sC[0][k] + sC[1][k] + sC[2][k] + sC[3][k];
            ws[P_CNT + (b * 4 + s) * 4 + k] = (float)cc;
        }
    }
}

// ---------------------------------------------------------------------------
// Finalize: sum partials, prototypes, normalize, align/sep, scalar out.
// one block, 256 threads.
// ---------------------------------------------------------------------------
__global__ __launch_bounds__(256) void finalize_kernel(
    const float* __restrict__ ws, float* __restrict__ out)
{
    __shared__ float sp[2048];          // proto [32][64]
    __shared__ float s_tw[32];
    __shared__ float s_cnt[8];
    __shared__ float s_scale[32];
    __shared__ float s_om[32];
    __shared__ int   s_valid[32];

    int tid = threadIdx.x;

    if (tid < 32) {                     // tw[bm][k], tid = bm*4+k
        int bm = tid >> 2, k = tid & 3;
        float t = 0.f;
        #pragma unroll
        for (int s = 0; s < 4; ++s) t += ws[P_TW + (bm * 4 + s) * 4 + k];
        s_tw[tid] = t;
    } else if (tid < 40) {              // cnt[b][k]
        int u = tid - 32, b = u >> 2, k = u & 3;
        float t = 0.f;
        #pragma unroll
        for (int s = 0; s < 4; ++s) t += ws[P_CNT + (b * 4 + s) * 4 + k];
        s_cnt[u] = t;
    }
    __syncthreads();

    // raw proto = num / (tw + EPS);  num[bm][k][c] = sum_s partial[bm][c][s][k]
    for (int i = tid; i < 2048; i += 256) {
        int p = i >> 6, c = i & 63;
        int bm = p >> 2, k = p & 3;
        float t = 0.f;
        #pragma unroll
        for (int s = 0; s < 4; ++s) t += ws[P_NUM + ((bm * C_ + c) * 4 + s) * 4 + k];
        sp[i] = t / (s_tw[p] + EPS_);
    }
    __syncthreads();

    if (tid < 32) {
        float ss = 0.f;
        for (int c = 0; c < 64; ++c) { float v = sp[tid * 64 + c]; ss += v * v; }
        float norm = sqrtf(fmaxf(ss, 1e-24f));          // NORM_EPS^2
        s_scale[tid] = 1.0f / fmaxf(norm, 1e-12f);
        int b = tid >> 4, k = tid & 3;
        float cc = s_cnt[b * 4 + k];
        s_om[tid] = (s_tw[tid] + EPS_) / (cc + EPS_);
        s_valid[tid] = (cc >= 1.0f) && (k != 0);
    }
    __syncthreads();
    for (int i = tid; i < 2048; i += 256) sp[i] *= s_scale[i >> 6];
    __syncthreads();

    float aS = 0.f, aC = 0.f, sS = 0.f, sC = 0.f;

    if (tid < 48) {                     // align: b(2) x mn-pair(6) x k(4)
        int b = tid / 24, r = tid % 24;
        int pr = r >> 2, k = r & 3;
        int p1 = (b * 4 + PM_[pr]) * 4 + k;
        int p2 = (b * 4 + PN_[pr]) * 4 + k;
        if (s_valid[p1] && s_valid[p2]) {
            float d = 0.f;
            for (int c = 0; c < 64; ++c) d += sp[p1 * 64 + c] * sp[p2 * 64 + c];
            aS = s_om[p1] * s_om[p2] * fmaxf(0.9f - d, 0.f);
            aC = 1.f;
        }
    } else if (tid >= 64 && tid < 112) { // sep: b(2) x m(4) x kl-pair(6)
        int t = tid - 64;
        int b = t / 24, r = t % 24;
        int m = r / 6, pr = r % 6;
        int bm = b * 4 + m;
        int p1 = bm * 4 + PM_[pr];
        int p2 = bm * 4 + PN_[pr];
        if (s_valid[p1] && s_valid[p2]) {
            float d = 0.f;
            for (int c = 0; c < 64; ++c) d += sp[p1 * 64 + c] * sp[p2 * 64 + c];
            sS = fmaxf(d - 0.1f, 0.f);
            sC = 1.f;
        }
    }

    #pragma unroll
    for (int off = 32; off; off >>= 1) {
        aS += __shfl_down(aS, off); aC += __shfl_down(aC, off);
        sS += __shfl_down(sS, off); sC += __shfl_down(sC, off);
    }
    __shared__ float red[4][4];
    int wid = tid >> 6, lane = tid & 63;
    if (lane == 0) { red[wid][0]=aS; red[wid][1]=aC; red[wid][2]=sS; red[wid][3]=sC; }
    __syncthreads();
    if (tid == 0) {
        float AS=0.f, AC=0.f, SS=0.f, SC=0.f;
        #pragma unroll
        for (int i = 0; i < 4; ++i) { AS+=red[i][0]; AC+=red[i][1]; SS+=red[i][2]; SC+=red[i][3]; }
        out[0] = AS / (AC + EPS_) + SS / (SC + EPS_);
    }
}

extern "C" void kernel_launch(void* const* d_in, const int* in_sizes, int n_in,
                              void* d_out, int out_size, void* d_ws, size_t ws_size,
                              hipStream_t stream)
{
    const float* feats   = (const float*)d_in[0];
    const float* weights = (const float*)d_in[1];
    const int*   target  = (const int*)d_in[2];
    float* out = (float*)d_out;
    float* ws  = (float*)d_ws;

    main_kernel<<<B_*M_*32*4, 256, 0, stream>>>(feats, weights, target, ws);
    finalize_kernel<<<1, 256, 0, stream>>>(ws, out);
}